// Round 1
// baseline (1362.322 us; speedup 1.0000x reference)
//
#include <hip/hip_runtime.h>

// RAVNet ragged attention block, fp32 baseline.
// B=4096 groups, C=81 classes, DK=64, N<=128 instances/group.
// One 256-thread block per group; flash-style attention with q/o in registers.

constexpr int C = 81;
constexpr int DK = 64;
constexpr int MAXN = 128;
constexpr int TILE = 32;
constexpr int OS_STRIDE = 68;   // o-row stride in LDS (16B-aligned, non-pow2)

// ---------------- Kernel 1: exclusive scan of counts -> offsets ----------------
__global__ void scan_counts(const int* __restrict__ counts,
                            int* __restrict__ offsets, int n) {
    __shared__ int part[256];
    int tid = threadIdx.x;
    int per = (n + 255) >> 8;
    int base = tid * per;
    int s = 0;
    for (int i = 0; i < per; i++) {
        int idx = base + i;
        if (idx < n) s += counts[idx];
    }
    part[tid] = s;
    __syncthreads();
    // Hillis-Steele inclusive scan over per-thread partials
    for (int off = 1; off < 256; off <<= 1) {
        int v = (tid >= off) ? part[tid - off] : 0;
        __syncthreads();
        part[tid] += v;
        __syncthreads();
    }
    int run = (tid == 0) ? 0 : part[tid - 1];
    for (int i = 0; i < per; i++) {
        int idx = base + i;
        if (idx < n) { offsets[idx] = run; run += counts[idx]; }
    }
}

// ---------------- Kernel 2: wpv = prior_rel @ wv  (81x81 @ 81x64) ----------------
__global__ void compute_wpv(const float* __restrict__ prior,
                            const float* __restrict__ wv,
                            float* __restrict__ wpv) {
    int idx = blockIdx.x * 256 + threadIdx.x;
    if (idx >= C * DK) return;
    int c = idx / DK, d = idx - (idx / DK) * DK;
    float s = 0.f;
    for (int e = 0; e < C; e++) s = fmaf(prior[c * C + e], wv[e * DK + d], s);
    wpv[idx] = s;
}

// ---------------- Kernel 3: per-group fused attention ----------------
__launch_bounds__(256, 2)
__global__ void ravnet_main(const float* __restrict__ x,
                            const int* __restrict__ counts,
                            const int* __restrict__ offsets,
                            const float* __restrict__ wq, const float* __restrict__ bq,
                            const float* __restrict__ wk, const float* __restrict__ bk,
                            const float* __restrict__ wpv, const float* __restrict__ bv,
                            const float* __restrict__ wu, const float* __restrict__ bu,
                            float* __restrict__ out) {
    // xs: staged x rows [N][81], stride 81 (odd -> conflict-free column reads).
    // Reused after attention as o rows [N][OS_STRIDE].
    __shared__ __align__(16) float xs[MAXN * C];      // 41.5 KB
    __shared__ __align__(16) float kt[TILE * DK];     // 8 KB
    __shared__ __align__(16) float vt[TILE * DK];     // 8 KB

    const int b    = blockIdx.x;
    const int N    = counts[b];
    const long off = offsets[b];
    const int tid  = threadIdx.x;
    const int lane = tid & 63;
    const int wave = tid >> 6;
    const int r    = wave * 32 + (lane & 31);  // query row this thread owns
    const int h    = lane >> 5;                // which 32-dim half of d_k

    // ---- Phase 1: stage x rows for this group ----
    const float* xsrc = x + off * C;
    for (int i = tid; i < N * C; i += 256) xs[i] = xsrc[i];
    __syncthreads();

    // ---- Phase 2a: q fragment (32 dims) into registers ----
    float qreg[32];
    if (r < N) {
        const float* bqh = bq + h * 32;
        #pragma unroll
        for (int g = 0; g < 8; g++) {
            float4 bb = *(const float4*)(bqh + g * 4);
            qreg[g*4+0] = bb.x; qreg[g*4+1] = bb.y;
            qreg[g*4+2] = bb.z; qreg[g*4+3] = bb.w;
        }
        const float* xr  = xs + r * C;
        const float* wqh = wq + h * 32;
        for (int c = 0; c < C; c++) {
            float xv = xr[c];
            const float4* w4 = (const float4*)(wqh + c * DK);
            #pragma unroll
            for (int g = 0; g < 8; g++) {
                float4 w = w4[g];
                qreg[g*4+0] = fmaf(xv, w.x, qreg[g*4+0]);
                qreg[g*4+1] = fmaf(xv, w.y, qreg[g*4+1]);
                qreg[g*4+2] = fmaf(xv, w.z, qreg[g*4+2]);
                qreg[g*4+3] = fmaf(xv, w.w, qreg[g*4+3]);
            }
        }
    } else {
        #pragma unroll
        for (int dd = 0; dd < 32; dd++) qreg[dd] = 0.f;
    }

    // ---- Phase 2b + 3: key tiles, flash-style online softmax ----
    float oreg[32];
    #pragma unroll
    for (int dd = 0; dd < 32; dd++) oreg[dd] = 0.f;
    float mrun = -1e30f, lrun = 0.f;

    const int d4  = (tid & 15) * 4;   // 4 consecutive d dims this thread produces
    const int tj0 = tid >> 4;         // tile row slot 0..15

    for (int jt = 0; jt < N; jt += TILE) {
        const int tlen = min(TILE, N - jt);
        // compute k,v for tile rows [jt, jt+tlen)
        #pragma unroll
        for (int ti = 0; ti < 2; ti++) {
            int tj = tj0 + ti * 16;
            if (tj < tlen) {
                const float* xr = xs + (jt + tj) * C;
                float a0 = bk[d4], a1 = bk[d4+1], a2 = bk[d4+2], a3 = bk[d4+3];
                float b0 = bv[d4], b1 = bv[d4+1], b2 = bv[d4+2], b3 = bv[d4+3];
                for (int c = 0; c < C; c++) {
                    float xv = xr[c];
                    float4 wkc = *(const float4*)(wk  + c * DK + d4);
                    float4 wvc = *(const float4*)(wpv + c * DK + d4);
                    a0 = fmaf(xv, wkc.x, a0); a1 = fmaf(xv, wkc.y, a1);
                    a2 = fmaf(xv, wkc.z, a2); a3 = fmaf(xv, wkc.w, a3);
                    b0 = fmaf(xv, wvc.x, b0); b1 = fmaf(xv, wvc.y, b1);
                    b2 = fmaf(xv, wvc.z, b2); b3 = fmaf(xv, wvc.w, b3);
                }
                *(float4*)(kt + tj * DK + d4) = make_float4(a0, a1, a2, a3);
                *(float4*)(vt + tj * DK + d4) = make_float4(b0, b1, b2, b3);
            }
        }
        __syncthreads();
        // online softmax over this tile's keys (all lanes run; invalid rows
        // have qreg=0 and their shfl partner shares the same row -> safe)
        for (int tj = 0; tj < tlen; tj++) {
            const float* kr = kt + tj * DK + h * 32;
            float s = 0.f;
            #pragma unroll
            for (int g = 0; g < 8; g++) {
                float4 kk = *(const float4*)(kr + g * 4);
                s = fmaf(qreg[g*4+0], kk.x, s);
                s = fmaf(qreg[g*4+1], kk.y, s);
                s = fmaf(qreg[g*4+2], kk.z, s);
                s = fmaf(qreg[g*4+3], kk.w, s);
            }
            s += __shfl_xor(s, 32, 64);   // combine the two 32-dim halves
            s *= 0.125f;                  // 1/sqrt(64)
            float mnew  = fmaxf(mrun, s);
            float scale = __expf(mrun - mnew);
            float p     = __expf(s - mnew);
            lrun = lrun * scale + p;
            mrun = mnew;
            const float* vr = vt + tj * DK + h * 32;
            #pragma unroll
            for (int g = 0; g < 8; g++) {
                float4 vv = *(const float4*)(vr + g * 4);
                oreg[g*4+0] = fmaf(oreg[g*4+0], scale, p * vv.x);
                oreg[g*4+1] = fmaf(oreg[g*4+1], scale, p * vv.y);
                oreg[g*4+2] = fmaf(oreg[g*4+2], scale, p * vv.z);
                oreg[g*4+3] = fmaf(oreg[g*4+3], scale, p * vv.w);
            }
        }
        __syncthreads();
    }

    // ---- Phase 4: normalize, stash o rows in LDS (overlay xs; xs is dead) ----
    if (r < N) {
        float linv = 1.0f / lrun;
        float* orow = xs + r * OS_STRIDE + h * 32;
        #pragma unroll
        for (int g = 0; g < 8; g++) {
            *(float4*)(orow + g * 4) = make_float4(oreg[g*4+0] * linv,
                                                   oreg[g*4+1] * linv,
                                                   oreg[g*4+2] * linv,
                                                   oreg[g*4+3] * linv);
        }
    }
    __syncthreads();

    // ---- Phase 5: final projection out[j] = o[j] @ wu + bu, scatter to flat ----
    const int tot = N * C;
    for (int idx = tid; idx < tot; idx += 256) {
        int j = idx / C;
        int e = idx - j * C;
        float acc = 0.f;
        const float* orow = xs + j * OS_STRIDE;
        #pragma unroll
        for (int g = 0; g < 16; g++) {
            float4 o4 = *(const float4*)(orow + g * 4);
            acc = fmaf(o4.x, wu[(g*4+0) * C + e], acc);
            acc = fmaf(o4.y, wu[(g*4+1) * C + e], acc);
            acc = fmaf(o4.z, wu[(g*4+2) * C + e], acc);
            acc = fmaf(o4.w, wu[(g*4+3) * C + e], acc);
        }
        out[off * C + idx] = acc + bu[e];
    }
}

// ---------------- launch ----------------
extern "C" void kernel_launch(void* const* d_in, const int* in_sizes, int n_in,
                              void* d_out, int out_size, void* d_ws, size_t ws_size,
                              hipStream_t stream) {
    const float* x      = (const float*)d_in[0];
    const int*   counts = (const int*)  d_in[1];
    const float* prior  = (const float*)d_in[2];
    const float* wq     = (const float*)d_in[3];
    const float* bq     = (const float*)d_in[4];
    const float* wk     = (const float*)d_in[5];
    const float* bk     = (const float*)d_in[6];
    const float* wv     = (const float*)d_in[7];
    const float* bv     = (const float*)d_in[8];
    const float* wu     = (const float*)d_in[9];
    const float* bu     = (const float*)d_in[10];
    float* out = (float*)d_out;

    const int B = in_sizes[1];   // 4096 groups

    int*   offsets = (int*)d_ws;
    float* wpv     = (float*)((char*)d_ws + (((size_t)B * sizeof(int) + 255) & ~(size_t)255));

    scan_counts<<<1, 256, 0, stream>>>(counts, offsets, B);
    compute_wpv<<<(C * DK + 255) / 256, 256, 0, stream>>>(prior, wv, wpv);
    ravnet_main<<<B, 256, 0, stream>>>(x, counts, offsets,
                                       wq, bq, wk, bk, wpv, bv, wu, bu, out);
}

// Round 2
// 336.867 us; speedup vs baseline: 4.0441x; 4.0441x over previous
//
#include <hip/hip_runtime.h>

// RAVNet ragged attention, bf16 MFMA version.
// B=4096 groups, C=81, DK=64, N<=128. One 256-thread block (4 waves) per group.
// All matmuls via v_mfma_f32_16x16x32_bf16; fp32 softmax; fp32 output.

typedef __attribute__((ext_vector_type(8))) short short8;   // 8 bf16 = 4 VGPRs
typedef __attribute__((ext_vector_type(4))) float f32x4;
typedef __attribute__((ext_vector_type(4))) short short4v;

constexpr int C  = 81;
constexpr int DK = 64;
constexpr int CP = 96;     // C padded to 3*32 for K-dim of projections

// ---- LDS layout (ushort units). Strides chosen for <=2-way bank aliasing ----
constexpr int XS_STRIDE = 104;  // x rows, 128x104 (52 dwords: 20r%32 -> 2-way)
constexpr int QK_STRIDE = 72;   // q/k rows   (36 dwords: 4r%32  -> 2-way)
constexpr int VT_STRIDE = 136;  // v^T rows   (68 dwords: 4r%32  -> 2-way)
constexpr int P_STRIDE  = 136;
constexpr int O_STRIDE  = 72;
constexpr int OFF_P  = 0;       // + wave*16*P_STRIDE   (overlays dead xs)
constexpr int OFF_O  = 8704;    // + wave*16*O_STRIDE   (overlays dead xs)
constexpr int OFF_Q  = 13312;   // 128*104
constexpr int OFF_K  = OFF_Q + 128 * QK_STRIDE;       // 22528
constexpr int OFF_VT = OFF_K + 128 * QK_STRIDE;       // 31744
constexpr int SMEM_TOT = OFF_VT + 64 * VT_STRIDE;     // 40448 ushorts = 80896 B

__device__ inline ushort f2b(float f) {   // fp32 -> bf16 bits, RNE
    uint u = __float_as_uint(f);
    uint r = (u + 0x7fffu + ((u >> 16) & 1u)) >> 16;
    return (ushort)r;
}

#define MFMA16(a, b, c) __builtin_amdgcn_mfma_f32_16x16x32_bf16((a), (b), (c), 0, 0, 0)

// ---------------- Kernel 1: exclusive scan of counts -> offsets ----------------
__global__ void scan_counts(const int* __restrict__ counts,
                            int* __restrict__ offsets, int n) {
    __shared__ int part[256];
    int tid = threadIdx.x;
    int per = (n + 255) >> 8;
    int base = tid * per;
    int s = 0;
    for (int i = 0; i < per; i++) {
        int idx = base + i;
        if (idx < n) s += counts[idx];
    }
    part[tid] = s;
    __syncthreads();
    for (int off = 1; off < 256; off <<= 1) {
        int v = (tid >= off) ? part[tid - off] : 0;
        __syncthreads();
        part[tid] += v;
        __syncthreads();
    }
    int run = (tid == 0) ? 0 : part[tid - 1];
    for (int i = 0; i < per; i++) {
        int idx = base + i;
        if (idx < n) { offsets[idx] = run; run += counts[idx]; }
    }
}

// ------- Kernel 2: weights -> bf16, transposed for contiguous B-fragments -------
// wqT/wkT/wvT: [64][96]  wT[n][k] = W[k][n] (k<81, else 0); wvT folds prior@wv.
// wuT: [96][64] wuT[n][k] = wu[k][n] (n<81, else 0).
__global__ void prep_weights(const float* __restrict__ prior,
                             const float* __restrict__ wq, const float* __restrict__ wk,
                             const float* __restrict__ wv, const float* __restrict__ wu,
                             ushort* __restrict__ wqT, ushort* __restrict__ wkT,
                             ushort* __restrict__ wvT, ushort* __restrict__ wuT) {
    int idx = blockIdx.x * 256 + threadIdx.x;
    int sec = idx / (DK * CP);
    int i   = idx - sec * (DK * CP);
    if (sec == 0 || sec == 1) {
        int n = i / CP, k = i - (i / CP) * CP;
        const float* w = (sec == 0) ? wq : wk;
        ushort* dst    = (sec == 0) ? wqT : wkT;
        dst[n * CP + k] = (k < C) ? f2b(w[k * DK + n]) : (ushort)0;
    } else if (sec == 2) {
        int n = i / CP, k = i - (i / CP) * CP;
        float s = 0.f;
        if (k < C)
            for (int e = 0; e < C; e++) s = fmaf(prior[k * C + e], wv[e * DK + n], s);
        wvT[n * CP + k] = (k < C) ? f2b(s) : (ushort)0;
    } else {
        int n = i / DK, k = i - (i / DK) * DK;   // n < 96, k < 64
        wuT[n * DK + k] = (n < C) ? f2b(wu[k * C + n]) : (ushort)0;
    }
}

// ---------------- Kernel 3: per-group MFMA attention ----------------
__launch_bounds__(256, 2)
__global__ void ravnet_mfma(const float* __restrict__ x,
                            const int* __restrict__ counts,
                            const int* __restrict__ offsets,
                            const ushort* __restrict__ wqT, const ushort* __restrict__ wkT,
                            const ushort* __restrict__ wvT, const ushort* __restrict__ wuT,
                            const float* __restrict__ bq, const float* __restrict__ bk,
                            const float* __restrict__ bv, const float* __restrict__ bu,
                            float* __restrict__ out) {
    __shared__ __align__(16) ushort sm[SMEM_TOT];   // 80,896 B -> 2 blocks/CU

    const int b    = blockIdx.x;
    const int N    = counts[b];
    const long off = offsets[b];
    const int tid  = threadIdx.x;
    const int lane = tid & 63;
    const int wave = tid >> 6;
    const int quad = lane >> 4;      // 0..3
    const int m16  = lane & 15;      // 0..15
    const int NT8  = (N + 15) >> 4;  // 16-row tiles, <=8
    const int NT4  = (N + 31) >> 5;  // 32-col K-steps for P@V, <=4
    const int R    = NT8 * 16;

    // ---- Phase 0: zero VT (padded cols must not be NaN), stage x -> bf16 ----
    uint* vt32 = (uint*)(sm + OFF_VT);
    for (int i = tid; i < (64 * VT_STRIDE) / 2; i += 256) vt32[i] = 0;
    const float* xsrc = x + off * C;
    uint* xs32 = (uint*)sm;
    const int tot0 = R * (XS_STRIDE / 2);
    for (int i = tid; i < tot0; i += 256) {
        int row = i / (XS_STRIDE / 2);
        int c0  = (i - row * (XS_STRIDE / 2)) * 2;
        float v0 = 0.f, v1 = 0.f;
        if (row < N) {
            if (c0 < C)     v0 = xsrc[row * C + c0];
            if (c0 + 1 < C) v1 = xsrc[row * C + c0 + 1];
        }
        xs32[i] = (uint)f2b(v0) | ((uint)f2b(v1) << 16);
    }
    __syncthreads();

    // ---- Phase 1: Q,K,V projections. Wave w owns output col-tile w (16 dims)
    // of each of Q, K, V. B-fragments (weights) hoisted across row-tiles. ----
    {
        const int n = wave * 16 + m16;   // output dim 0..63
        for (int mat = 0; mat < 3; mat++) {
            const ushort* wT = (mat == 0) ? wqT : (mat == 1) ? wkT : wvT;
            const float*  bs = (mat == 0) ? bq  : (mat == 1) ? bk  : bv;
            short8 bfr[3];
            #pragma unroll
            for (int ks = 0; ks < 3; ks++)
                bfr[ks] = *(const short8*)(wT + n * CP + ks * 32 + quad * 8);
            float bval = bs[n];
            for (int rt = 0; rt < NT8; rt++) {
                f32x4 acc = {0.f, 0.f, 0.f, 0.f};
                #pragma unroll
                for (int ks = 0; ks < 3; ks++) {
                    short8 a = *(const short8*)(sm + (rt * 16 + m16) * XS_STRIDE +
                                                ks * 32 + quad * 8);
                    acc = MFMA16(a, bfr[ks], acc);
                }
                int r0 = rt * 16 + quad * 4;
                if (mat < 2) {   // row-major q/k (A / B operand of QK^T)
                    ushort* dst = sm + ((mat == 0) ? OFF_Q : OFF_K);
                    #pragma unroll
                    for (int r = 0; r < 4; r++)
                        dst[(r0 + r) * QK_STRIDE + n] = f2b(acc[r] + bval);
                } else {         // v transposed: VT[d][inst], 4 contiguous -> 8B store
                    short4v pk;
                    #pragma unroll
                    for (int r = 0; r < 4; r++) pk[r] = (short)f2b(acc[r] + bval);
                    *(short4v*)(sm + OFF_VT + n * VT_STRIDE + r0) = pk;
                }
            }
        }
    }
    __syncthreads();

    // ---- Phase 2: attention + output projection, one Q-row-tile per wave-iter ----
    for (int qt = wave; qt < NT8; qt += 4) {
        short8 aq[2];
        #pragma unroll
        for (int ks = 0; ks < 2; ks++)
            aq[ks] = *(const short8*)(sm + OFF_Q + (qt * 16 + m16) * QK_STRIDE +
                                      ks * 32 + quad * 8);
        // S = Q K^T (full row block in registers, C-layout)
        f32x4 sacc[8];
        #pragma unroll
        for (int ct = 0; ct < 8; ct++) {
            if (ct < NT8) {
                f32x4 a = {0.f, 0.f, 0.f, 0.f};
                #pragma unroll
                for (int ks = 0; ks < 2; ks++) {
                    short8 kb = *(const short8*)(sm + OFF_K + (ct * 16 + m16) * QK_STRIDE +
                                                 ks * 32 + quad * 8);
                    a = MFMA16(aq[ks], kb, a);
                }
                sacc[ct] = a;
            }
        }
        // scale + key-col mask + row max (rows live in quads; reduce across m16)
        float mr[4] = {-3e38f, -3e38f, -3e38f, -3e38f};
        #pragma unroll
        for (int ct = 0; ct < 8; ct++) if (ct < NT8) {
            bool valid = (ct * 16 + m16) < N;
            #pragma unroll
            for (int r = 0; r < 4; r++) {
                float s = valid ? sacc[ct][r] * 0.125f : -3e38f;
                sacc[ct][r] = s;
                mr[r] = fmaxf(mr[r], s);
            }
        }
        #pragma unroll
        for (int r = 0; r < 4; r++) {
            mr[r] = fmaxf(mr[r], __shfl_xor(mr[r], 1, 64));
            mr[r] = fmaxf(mr[r], __shfl_xor(mr[r], 2, 64));
            mr[r] = fmaxf(mr[r], __shfl_xor(mr[r], 4, 64));
            mr[r] = fmaxf(mr[r], __shfl_xor(mr[r], 8, 64));
        }
        float lr[4] = {0.f, 0.f, 0.f, 0.f};
        #pragma unroll
        for (int ct = 0; ct < 8; ct++) if (ct < NT8) {
            #pragma unroll
            for (int r = 0; r < 4; r++) {
                float p = __expf(sacc[ct][r] - mr[r]);
                sacc[ct][r] = p;
                lr[r] += p;
            }
        }
        #pragma unroll
        for (int r = 0; r < 4; r++) {
            lr[r] += __shfl_xor(lr[r], 1, 64);
            lr[r] += __shfl_xor(lr[r], 2, 64);
            lr[r] += __shfl_xor(lr[r], 4, 64);
            lr[r] += __shfl_xor(lr[r], 8, 64);
        }
        // P -> LDS (C-layout scatter), then re-read as A-fragments
        ushort* P = sm + OFF_P + wave * (16 * P_STRIDE);
        #pragma unroll
        for (int ct = 0; ct < 8; ct++) if (ct < NT8) {
            #pragma unroll
            for (int r = 0; r < 4; r++)
                P[(quad * 4 + r) * P_STRIDE + ct * 16 + m16] = f2b(sacc[ct][r]);
        }
        if (NT8 & 1) {   // zero pad cols [NT8*16, NT4*32)
            #pragma unroll
            for (int r = 0; r < 4; r++)
                P[(quad * 4 + r) * P_STRIDE + NT8 * 16 + m16] = 0;
        }
        __threadfence_block();
        short8 ap[4];
        #pragma unroll
        for (int kt = 0; kt < 4; kt++) if (kt < NT4)
            ap[kt] = *(const short8*)(P + m16 * P_STRIDE + kt * 32 + quad * 8);
        // O = P V (B from VT), normalize by row sum, stage bf16 O
        float linv[4];
        #pragma unroll
        for (int r = 0; r < 4; r++) linv[r] = (lr[r] > 0.f) ? 1.f / lr[r] : 0.f;
        ushort* O = sm + OFF_O + wave * (16 * O_STRIDE);
        #pragma unroll
        for (int ot = 0; ot < 4; ot++) {
            f32x4 oa = {0.f, 0.f, 0.f, 0.f};
            #pragma unroll
            for (int kt = 0; kt < 4; kt++) if (kt < NT4) {
                short8 vb = *(const short8*)(sm + OFF_VT + (ot * 16 + m16) * VT_STRIDE +
                                             kt * 32 + quad * 8);
                oa = MFMA16(ap[kt], vb, oa);
            }
            #pragma unroll
            for (int r = 0; r < 4; r++)
                O[(quad * 4 + r) * O_STRIDE + ot * 16 + m16] = f2b(oa[r] * linv[r]);
        }
        __threadfence_block();
        short8 ao[2];
        #pragma unroll
        for (int ks = 0; ks < 2; ks++)
            ao[ks] = *(const short8*)(O + m16 * O_STRIDE + ks * 32 + quad * 8);
        // out = O @ Wu + bu, masked scatter to ragged flat layout
        #pragma unroll
        for (int ct = 0; ct < 6; ct++) {
            f32x4 acc = {0.f, 0.f, 0.f, 0.f};
            #pragma unroll
            for (int ks = 0; ks < 2; ks++) {
                short8 wb = *(const short8*)(wuT + (ct * 16 + m16) * DK + ks * 32 + quad * 8);
                acc = MFMA16(ao[ks], wb, acc);
            }
            int e = ct * 16 + m16;
            if (e < C) {
                float bue = bu[e];
                #pragma unroll
                for (int r = 0; r < 4; r++) {
                    int row = qt * 16 + quad * 4 + r;
                    if (row < N) out[(off + row) * C + e] = acc[r] + bue;
                }
            }
        }
    }
}

// ---------------- launch ----------------
extern "C" void kernel_launch(void* const* d_in, const int* in_sizes, int n_in,
                              void* d_out, int out_size, void* d_ws, size_t ws_size,
                              hipStream_t stream) {
    const float* x      = (const float*)d_in[0];
    const int*   counts = (const int*)  d_in[1];
    const float* prior  = (const float*)d_in[2];
    const float* wq     = (const float*)d_in[3];
    const float* bq     = (const float*)d_in[4];
    const float* wk     = (const float*)d_in[5];
    const float* bk     = (const float*)d_in[6];
    const float* wv     = (const float*)d_in[7];
    const float* bv     = (const float*)d_in[8];
    const float* wu     = (const float*)d_in[9];
    const float* bu     = (const float*)d_in[10];
    float* out = (float*)d_out;

    const int B = in_sizes[1];   // 4096 groups

    // ws: offsets[B] | wqT | wkT | wvT | wuT  (bf16, transposed, padded)
    int*    offsets = (int*)d_ws;
    ushort* wqT = (ushort*)((char*)d_ws + (((size_t)B * sizeof(int) + 255) & ~(size_t)255));
    ushort* wkT = wqT + DK * CP;
    ushort* wvT = wkT + DK * CP;
    ushort* wuT = wvT + DK * CP;

    scan_counts<<<1, 256, 0, stream>>>(counts, offsets, B);
    prep_weights<<<(4 * DK * CP + 255) / 256, 256, 0, stream>>>(
        prior, wq, wk, wv, wu, wqT, wkT, wvT, wuT);
    ravnet_mfma<<<B, 256, 0, stream>>>(x, counts, offsets,
                                       wqT, wkT, wvT, wuT,
                                       bq, bk, bv, bu, out);
}